// Round 3
// baseline (591.384 us; speedup 1.0000x reference)
//
#include <hip/hip_runtime.h>

typedef unsigned short u16t;
typedef __attribute__((ext_vector_type(8))) short short8;
typedef __attribute__((ext_vector_type(4))) float f32x4;
typedef __attribute__((ext_vector_type(4))) unsigned short u16x4;

__device__ __forceinline__ float bf2f(short b) {
  return __uint_as_float(((unsigned)(unsigned short)b) << 16);
}
__device__ __forceinline__ u16t f2bf(float f) {
  unsigned u = __float_as_uint(f);
  u += 0x7FFFu + ((u >> 16) & 1u);  // RNE
  return (u16t)(u >> 16);
}

// jax threefry2x32, key = (0, 42); partitionable counter scheme:
// counter = flat u64 -> (hi=0, lo=flat); bits = o0 ^ o1; keep = top bit 0 (p=0.5)
__device__ __forceinline__ bool keep_mask(unsigned flat) {
  const unsigned k0 = 0u, k1 = 42u;
  const unsigned k2 = k0 ^ k1 ^ 0x1BD11BDAu;
  unsigned x0 = 0u + k0;
  unsigned x1 = flat + k1;
#define TF_R(r) { x0 += x1; x1 = (x1 << r) | (x1 >> (32 - r)); x1 ^= x0; }
  TF_R(13) TF_R(15) TF_R(26) TF_R(6)  x0 += k1; x1 += k2 + 1u;
  TF_R(17) TF_R(29) TF_R(16) TF_R(24) x0 += k2; x1 += k0 + 2u;
  TF_R(13) TF_R(15) TF_R(26) TF_R(6)  x0 += k0; x1 += k1 + 3u;
  TF_R(17) TF_R(29) TF_R(16) TF_R(24) x0 += k1; x1 += k2 + 4u;
  TF_R(13) TF_R(15) TF_R(26) TF_R(6)  x0 += k2; x1 += k0 + 5u;
#undef TF_R
  return ((x0 ^ x1) >> 31) == 0u;
}

__device__ __forceinline__ void load_lds16(const u16t* g, u16t* l) {
  __builtin_amdgcn_global_load_lds((__attribute__((address_space(1))) void*)g,
                                   (__attribute__((address_space(3))) void*)l,
                                   16, 0, 0);
}

// ---- f32 -> bf16 conversion (n divisible by 4) ----
__global__ void cvt_bf16(const float* __restrict__ s, u16t* __restrict__ d, int n) {
  int i = (blockIdx.x * 256 + threadIdx.x) * 4;
  if (i < n) {
    f32x4 v = *(const f32x4*)&s[i];
    u16x4 o = { f2bf(v.x), f2bf(v.y), f2bf(v.z), f2bf(v.w) };
    *(u16x4*)&d[i] = o;
  }
}

// ---- CSR build ----
__global__ void count_edges(const int* __restrict__ dst, int E, int* __restrict__ cnt) {
  int e = blockIdx.x * 256 + threadIdx.x;
  if (e < E) atomicAdd(&cnt[dst[e]], 1);
}

// Parallel row-pointer build: block-local exclusive scan + one global atomic per
// block. Row ranges land in nondeterministic order, but each node's slice is
// private, so results are identical.
__global__ __launch_bounds__(256) void rowp_build(const int* __restrict__ cnt,
    int* __restrict__ rowp, int* __restrict__ cursor, float* __restrict__ dinv,
    int* __restrict__ gctr, int n) {
  __shared__ int sd[256];
  __shared__ int sbase;
  const int tid = threadIdx.x;
  const int i = blockIdx.x * 256 + tid;
  int c = (i < n) ? cnt[i] : 0;
  int v = c;
  sd[tid] = v;
  __syncthreads();
  for (int o = 1; o < 256; o <<= 1) {
    int t = (tid >= o) ? sd[tid - o] : 0;
    __syncthreads();
    v += t;
    sd[tid] = v;
    __syncthreads();
  }
  if (tid == 255) sbase = atomicAdd(gctr, v);  // v == block total
  __syncthreads();
  if (i < n) {
    int start = sbase + v - c;
    rowp[i] = start;
    cursor[i] = start;
    dinv[i] = rsqrtf((float)(c + 1));  // +1 self loop
  }
}

__global__ void fill_csr(const int* __restrict__ src, const int* __restrict__ dst, int E,
                         int* __restrict__ cursor, int* __restrict__ col) {
  int e = blockIdx.x * 256 + threadIdx.x;
  if (e < E) {
    int d = dst[e];
    int pos = atomicAdd(&cursor[d], 1);
    col[pos] = src[e];
  }
  // after this kernel, cursor[i] == row end offset
}

// ---- m97-style bf16 GEMM: C[m,n] = sum_k A[m,k]*B[n,k]
// Grid: x = n-tile (FASTEST -> consecutive blocks share the A m-tile via L2),
//       y = m-tile. A is effectively read once from HBM instead of Ncols/128 x.
__global__ __launch_bounds__(256) void gemm_bt(const u16t* __restrict__ A,
                                               const u16t* __restrict__ B,
                                               u16t* __restrict__ C,
                                               int K, int Ncols) {
  __shared__ __align__(16) u16t lA[128 * 32];
  __shared__ __align__(16) u16t lB[128 * 32];
  const int tid = threadIdx.x;
  const int wave = tid >> 6, lane = tid & 63;
  const int wm = (wave & 1) * 64, wn = (wave >> 1) * 64;
  const int lrow = lane & 15, lq = lane >> 4;
  const u16t* Ab = A + (size_t)blockIdx.y * 128 * K;
  const u16t* Bb = B + (size_t)blockIdx.x * 128 * K;
  const int r0 = tid >> 2, c0 = (tid & 3) * 8;
  const int ldsOff = __builtin_amdgcn_readfirstlane((tid >> 6) * 512);

  f32x4 acc[4][4];
  const f32x4 zero = {0.f, 0.f, 0.f, 0.f};
#pragma unroll
  for (int mi = 0; mi < 4; ++mi)
#pragma unroll
    for (int ni = 0; ni < 4; ++ni) acc[mi][ni] = zero;

  for (int kt = 0; kt < K; kt += 32) {
    __syncthreads();
    load_lds16(Ab + (size_t)r0 * K + kt + c0, &lA[ldsOff]);
    load_lds16(Ab + (size_t)(r0 + 64) * K + kt + c0, &lA[2048 + ldsOff]);
    load_lds16(Bb + (size_t)r0 * K + kt + c0, &lB[ldsOff]);
    load_lds16(Bb + (size_t)(r0 + 64) * K + kt + c0, &lB[2048 + ldsOff]);
    __syncthreads();
    short8 af[4], bfr[4];
#pragma unroll
    for (int mi = 0; mi < 4; ++mi)
      af[mi] = *(const short8*)&lA[(wm + mi * 16 + lrow) * 32 + lq * 8];
#pragma unroll
    for (int ni = 0; ni < 4; ++ni)
      bfr[ni] = *(const short8*)&lB[(wn + ni * 16 + lrow) * 32 + lq * 8];
#pragma unroll
    for (int mi = 0; mi < 4; ++mi)
#pragma unroll
      for (int ni = 0; ni < 4; ++ni)
        acc[mi][ni] = __builtin_amdgcn_mfma_f32_16x16x32_bf16(af[mi], bfr[ni], acc[mi][ni], 0, 0, 0);
  }

  const size_t crow = (size_t)blockIdx.y * 128 + wm + lq * 4;
  const int ccol = blockIdx.x * 128 + wn + lrow;
#pragma unroll
  for (int mi = 0; mi < 4; ++mi)
#pragma unroll
    for (int r = 0; r < 4; ++r)
#pragma unroll
      for (int ni = 0; ni < 4; ++ni)
        C[(crow + mi * 16 + r) * Ncols + ccol + ni * 16] = f2bf(acc[mi][ni][r]);
}

// ---- propagate layer 1 + bias + relu + dropout; writes emb f32 (d_out) + emb bf16 (ws)
// 8-way unrolled gather: 8 independent 1KB row loads in flight per wave.
__global__ __launch_bounds__(256) void prop1_kernel(const u16t* __restrict__ y1,
    const int* __restrict__ col, const int* __restrict__ rowp, const int* __restrict__ rowend,
    const float* __restrict__ dinv, const float* __restrict__ b1,
    float* __restrict__ embf, u16t* __restrict__ embb, int n) {
  const int lane = threadIdx.x & 63;
  const int i = blockIdx.x * 4 + (threadIdx.x >> 6);
  if (i >= n) return;
  const int f = lane * 8;
  const float di = dinv[i];
  float acc[8];
  short8 v = *(const short8*)&y1[(size_t)i * 512 + f];
#pragma unroll
  for (int j = 0; j < 8; ++j) acc[j] = di * bf2f(v[j]);
  int e = rowp[i];
  const int e1 = rowend[i];
  for (; e + 8 <= e1; e += 8) {
    int s[8];
    float w[8];
    short8 u[8];
#pragma unroll
    for (int q = 0; q < 8; ++q) s[q] = col[e + q];
#pragma unroll
    for (int q = 0; q < 8; ++q) w[q] = dinv[s[q]];
#pragma unroll
    for (int q = 0; q < 8; ++q) u[q] = *(const short8*)&y1[(size_t)s[q] * 512 + f];
#pragma unroll
    for (int q = 0; q < 8; ++q)
#pragma unroll
      for (int j = 0; j < 8; ++j) acc[j] += w[q] * bf2f(u[q][j]);
  }
  for (; e + 4 <= e1; e += 4) {
    int s[4];
    float w[4];
    short8 u[4];
#pragma unroll
    for (int q = 0; q < 4; ++q) s[q] = col[e + q];
#pragma unroll
    for (int q = 0; q < 4; ++q) w[q] = dinv[s[q]];
#pragma unroll
    for (int q = 0; q < 4; ++q) u[q] = *(const short8*)&y1[(size_t)s[q] * 512 + f];
#pragma unroll
    for (int q = 0; q < 4; ++q)
#pragma unroll
      for (int j = 0; j < 8; ++j) acc[j] += w[q] * bf2f(u[q][j]);
  }
  for (; e < e1; ++e) {
    const int s = col[e];
    const float w = dinv[s];
    short8 u = *(const short8*)&y1[(size_t)s * 512 + f];
#pragma unroll
    for (int j = 0; j < 8; ++j) acc[j] += w * bf2f(u[j]);
  }
  const unsigned flat = (unsigned)i * 512u + (unsigned)f;
  f32x4 o0, o1;
  short8 ob;
#pragma unroll
  for (int j = 0; j < 8; ++j) {
    float h = di * acc[j] + b1[f + j];
    h = fmaxf(h, 0.f);
    float eb = keep_mask(flat + (unsigned)j) ? 2.f * h : 0.f;
    if (j < 4) o0[j] = eb; else o1[j - 4] = eb;
    ob[j] = (short)f2bf(eb);
  }
  *(f32x4*)&embf[(size_t)i * 512 + f] = o0;
  *(f32x4*)&embf[(size_t)i * 512 + f + 4] = o1;
  *(short8*)&embb[(size_t)i * 512 + f] = ob;
}

// ---- propagate layer 2 + bias; writes out f32
// 2 nodes per wave: 32 lanes x 8 feats (16B/lane loads), 4-way unrolled.
__global__ __launch_bounds__(256) void prop2_kernel(const u16t* __restrict__ z,
    const int* __restrict__ col, const int* __restrict__ rowp, const int* __restrict__ rowend,
    const float* __restrict__ dinv, const float* __restrict__ b2,
    float* __restrict__ outp, int n) {
  const int h = threadIdx.x & 31;                   // lane within half-wave
  const int i = blockIdx.x * 8 + (threadIdx.x >> 5);
  if (i >= n) return;
  const int f = h * 8;
  const float di = dinv[i];
  float acc[8];
  short8 v = *(const short8*)&z[(size_t)i * 256 + f];
#pragma unroll
  for (int j = 0; j < 8; ++j) acc[j] = di * bf2f(v[j]);
  int e = rowp[i];
  const int e1 = rowend[i];
  for (; e + 4 <= e1; e += 4) {
    int s[4];
    float w[4];
    short8 u[4];
#pragma unroll
    for (int q = 0; q < 4; ++q) s[q] = col[e + q];
#pragma unroll
    for (int q = 0; q < 4; ++q) w[q] = dinv[s[q]];
#pragma unroll
    for (int q = 0; q < 4; ++q) u[q] = *(const short8*)&z[(size_t)s[q] * 256 + f];
#pragma unroll
    for (int q = 0; q < 4; ++q)
#pragma unroll
      for (int j = 0; j < 8; ++j) acc[j] += w[q] * bf2f(u[q][j]);
  }
  for (; e < e1; ++e) {
    const int s = col[e];
    const float w = dinv[s];
    short8 u = *(const short8*)&z[(size_t)s * 256 + f];
#pragma unroll
    for (int j = 0; j < 8; ++j) acc[j] += w * bf2f(u[j]);
  }
  f32x4 o0, o1;
#pragma unroll
  for (int j = 0; j < 8; ++j) {
    float r = di * acc[j] + b2[f + j];
    if (j < 4) o0[j] = r; else o1[j - 4] = r;
  }
  *(f32x4*)&outp[(size_t)i * 256 + f] = o0;
  *(f32x4*)&outp[(size_t)i * 256 + f + 4] = o1;
}

extern "C" void kernel_launch(void* const* d_in, const int* in_sizes, int n_in,
                              void* d_out, int out_size, void* d_ws, size_t ws_size,
                              hipStream_t stream) {
  (void)n_in; (void)out_size; (void)ws_size;
  const float* x  = (const float*)d_in[0];
  const int*   ei = (const int*)d_in[1];    // [2][E]: src row then dst row
  const float* W1 = (const float*)d_in[2];
  const float* b1 = (const float*)d_in[3];
  const float* W2 = (const float*)d_in[4];
  const float* b2 = (const float*)d_in[5];

  const int Nn = in_sizes[0] / 512;             // 50000
  const int E  = in_sizes[1] / 2;               // 800000
  const int Mpad = ((Nn + 127) / 128) * 128;    // 50048
  const int K = 512;

  char* ws = (char*)d_ws;
  size_t off = 0;
  auto take = [&](size_t bytes) -> char* {
    char* p = ws + off;
    off += (bytes + 255) & ~(size_t)255;
    return p;
  };
  u16t* xb   = (u16t*)take((size_t)Mpad * 512 * 2);  // x bf16; later reused as emb bf16
  u16t* y1b  = (u16t*)take((size_t)Mpad * 512 * 2);  // y1 = x@W1^T bf16; later reused as z
  u16t* W1b  = (u16t*)take((size_t)512 * 512 * 2);
  u16t* W2b  = (u16t*)take((size_t)256 * 512 * 2);
  int*   cnt    = (int*)take((size_t)(Nn + 1) * 4);  // cnt[Nn] is the global cursor
  int*   rowp   = (int*)take((size_t)Nn * 4);
  int*   cursor = (int*)take((size_t)Nn * 4);
  float* dinv   = (float*)take((size_t)Nn * 4);
  int*   colA   = (int*)take((size_t)E * 4);

  float* embf = (float*)d_out;                       // [Nn,512]
  float* outf = (float*)d_out + (size_t)Nn * 512;    // [Nn,256]

  hipMemsetAsync(cnt, 0, (size_t)(Nn + 1) * 4, stream);

  const int n1 = Nn * 512;
  cvt_bf16<<<(n1 / 4 + 255) / 256, 256, 0, stream>>>(x, xb, n1);
  cvt_bf16<<<(512 * 512 / 4 + 255) / 256, 256, 0, stream>>>(W1, W1b, 512 * 512);
  cvt_bf16<<<(256 * 512 / 4 + 255) / 256, 256, 0, stream>>>(W2, W2b, 256 * 512);

  count_edges<<<(E + 255) / 256, 256, 0, stream>>>(ei + E, E, cnt);
  rowp_build<<<(Nn + 255) / 256, 256, 0, stream>>>(cnt, rowp, cursor, dinv, cnt + Nn, Nn);
  fill_csr<<<(E + 255) / 256, 256, 0, stream>>>(ei, ei + E, E, cursor, colA);

  // layer 1: y1 = x @ W1^T (bf16), then propagate (P commutes with right-mul)
  dim3 g1(512 / 128, Mpad / 128);   // x = n-tile fastest -> A-tile L2 reuse
  gemm_bt<<<g1, 256, 0, stream>>>(xb, W1b, y1b, K, 512);
  prop1_kernel<<<(Nn + 3) / 4, 256, 0, stream>>>(y1b, colA, rowp, cursor, dinv, b1,
                                                 embf, xb /* emb bf16, aliases xb */, Nn);

  // layer 2: z = emb @ W2^T (bf16), then propagate + b2
  u16t* zb = y1b;  // alias: y1 dead after prop1
  dim3 g2(256 / 128, Mpad / 128);
  gemm_bt<<<g2, 256, 0, stream>>>(xb, W2b, zb, K, 256);
  prop2_kernel<<<(Nn + 7) / 8, 256, 0, stream>>>(zb, colA, rowp, cursor, dinv, b2, outf, Nn);
}

// Round 4
// 590.916 us; speedup vs baseline: 1.0008x; 1.0008x over previous
//
#include <hip/hip_runtime.h>

typedef unsigned short u16t;
typedef __attribute__((ext_vector_type(8))) short short8;
typedef __attribute__((ext_vector_type(4))) short short4v;
typedef __attribute__((ext_vector_type(2))) short short2v;
typedef __attribute__((ext_vector_type(4))) float f32x4;
typedef __attribute__((ext_vector_type(2))) float f32x2;
typedef __attribute__((ext_vector_type(4))) unsigned short u16x4;

__device__ __forceinline__ float bf2f(short b) {
  return __uint_as_float(((unsigned)(unsigned short)b) << 16);
}
__device__ __forceinline__ u16t f2bf(float f) {
  unsigned u = __float_as_uint(f);
  u += 0x7FFFu + ((u >> 16) & 1u);  // RNE
  return (u16t)(u >> 16);
}

// jax threefry2x32, key = (0, 42); partitionable counter scheme:
// counter = flat u64 -> (hi=0, lo=flat); bits = o0 ^ o1; keep = top bit 0 (p=0.5)
__device__ __forceinline__ bool keep_mask(unsigned flat) {
  const unsigned k0 = 0u, k1 = 42u;
  const unsigned k2 = k0 ^ k1 ^ 0x1BD11BDAu;
  unsigned x0 = 0u + k0;
  unsigned x1 = flat + k1;
#define TF_R(r) { x0 += x1; x1 = (x1 << r) | (x1 >> (32 - r)); x1 ^= x0; }
  TF_R(13) TF_R(15) TF_R(26) TF_R(6)  x0 += k1; x1 += k2 + 1u;
  TF_R(17) TF_R(29) TF_R(16) TF_R(24) x0 += k2; x1 += k0 + 2u;
  TF_R(13) TF_R(15) TF_R(26) TF_R(6)  x0 += k0; x1 += k1 + 3u;
  TF_R(17) TF_R(29) TF_R(16) TF_R(24) x0 += k1; x1 += k2 + 4u;
  TF_R(13) TF_R(15) TF_R(26) TF_R(6)  x0 += k2; x1 += k0 + 5u;
#undef TF_R
  return ((x0 ^ x1) >> 31) == 0u;
}

__device__ __forceinline__ void load_lds16(const u16t* g, u16t* l) {
  __builtin_amdgcn_global_load_lds((__attribute__((address_space(1))) void*)g,
                                   (__attribute__((address_space(3))) void*)l,
                                   16, 0, 0);
}

// ---- f32 -> bf16 conversion (n divisible by 4) ----
__global__ void cvt_bf16(const float* __restrict__ s, u16t* __restrict__ d, int n) {
  int i = (blockIdx.x * 256 + threadIdx.x) * 4;
  if (i < n) {
    f32x4 v = *(const f32x4*)&s[i];
    u16x4 o = { f2bf(v.x), f2bf(v.y), f2bf(v.z), f2bf(v.w) };
    *(u16x4*)&d[i] = o;
  }
}

// ---- CSR build ----
__global__ void count_edges(const int* __restrict__ dst, int E, int* __restrict__ cnt) {
  int e = blockIdx.x * 256 + threadIdx.x;
  if (e < E) atomicAdd(&cnt[dst[e]], 1);
}

// Parallel row-pointer build: block-local scan + one global atomic per block.
__global__ __launch_bounds__(256) void rowp_build(const int* __restrict__ cnt,
    int* __restrict__ rowp, int* __restrict__ cursor, float* __restrict__ dinv,
    int* __restrict__ gctr, int n) {
  __shared__ int sd[256];
  __shared__ int sbase;
  const int tid = threadIdx.x;
  const int i = blockIdx.x * 256 + tid;
  int c = (i < n) ? cnt[i] : 0;
  int v = c;
  sd[tid] = v;
  __syncthreads();
  for (int o = 1; o < 256; o <<= 1) {
    int t = (tid >= o) ? sd[tid - o] : 0;
    __syncthreads();
    v += t;
    sd[tid] = v;
    __syncthreads();
  }
  if (tid == 255) sbase = atomicAdd(gctr, v);
  __syncthreads();
  if (i < n) {
    int start = sbase + v - c;
    rowp[i] = start;
    cursor[i] = start;
    dinv[i] = rsqrtf((float)(c + 1));  // +1 self loop
  }
}

__global__ void fill_csr(const int* __restrict__ src, const int* __restrict__ dst, int E,
                         int* __restrict__ cursor, int* __restrict__ col) {
  int e = blockIdx.x * 256 + threadIdx.x;
  if (e < E) {
    int d = dst[e];
    int pos = atomicAdd(&cursor[d], 1);
    col[pos] = src[e];
  }
  // after this kernel, cursor[i] == row end offset
}

// ---- m97-style bf16 GEMM: C[m,n] = sum_k A[m,k]*B[n,k]; grid x = n-tile (fastest)
__global__ __launch_bounds__(256) void gemm_bt(const u16t* __restrict__ A,
                                               const u16t* __restrict__ B,
                                               u16t* __restrict__ C,
                                               int K, int Ncols) {
  __shared__ __align__(16) u16t lA[128 * 32];
  __shared__ __align__(16) u16t lB[128 * 32];
  const int tid = threadIdx.x;
  const int wave = tid >> 6, lane = tid & 63;
  const int wm = (wave & 1) * 64, wn = (wave >> 1) * 64;
  const int lrow = lane & 15, lq = lane >> 4;
  const u16t* Ab = A + (size_t)blockIdx.y * 128 * K;
  const u16t* Bb = B + (size_t)blockIdx.x * 128 * K;
  const int r0 = tid >> 2, c0 = (tid & 3) * 8;
  const int ldsOff = __builtin_amdgcn_readfirstlane((tid >> 6) * 512);

  f32x4 acc[4][4];
  const f32x4 zero = {0.f, 0.f, 0.f, 0.f};
#pragma unroll
  for (int mi = 0; mi < 4; ++mi)
#pragma unroll
    for (int ni = 0; ni < 4; ++ni) acc[mi][ni] = zero;

  for (int kt = 0; kt < K; kt += 32) {
    __syncthreads();
    load_lds16(Ab + (size_t)r0 * K + kt + c0, &lA[ldsOff]);
    load_lds16(Ab + (size_t)(r0 + 64) * K + kt + c0, &lA[2048 + ldsOff]);
    load_lds16(Bb + (size_t)r0 * K + kt + c0, &lB[ldsOff]);
    load_lds16(Bb + (size_t)(r0 + 64) * K + kt + c0, &lB[2048 + ldsOff]);
    __syncthreads();
    short8 af[4], bfr[4];
#pragma unroll
    for (int mi = 0; mi < 4; ++mi)
      af[mi] = *(const short8*)&lA[(wm + mi * 16 + lrow) * 32 + lq * 8];
#pragma unroll
    for (int ni = 0; ni < 4; ++ni)
      bfr[ni] = *(const short8*)&lB[(wn + ni * 16 + lrow) * 32 + lq * 8];
#pragma unroll
    for (int mi = 0; mi < 4; ++mi)
#pragma unroll
      for (int ni = 0; ni < 4; ++ni)
        acc[mi][ni] = __builtin_amdgcn_mfma_f32_16x16x32_bf16(af[mi], bfr[ni], acc[mi][ni], 0, 0, 0);
  }

  const size_t crow = (size_t)blockIdx.y * 128 + wm + lq * 4;
  const int ccol = blockIdx.x * 128 + wn + lrow;
#pragma unroll
  for (int mi = 0; mi < 4; ++mi)
#pragma unroll
    for (int r = 0; r < 4; ++r)
#pragma unroll
      for (int ni = 0; ni < 4; ++ni)
        C[(crow + mi * 16 + r) * Ncols + ccol + ni * 16] = f2bf(acc[mi][ni][r]);
}

// ---- propagate layer 1, feature-split-2 with XCD affinity ----
// Mapping: slot = blockIdx%8 -> XCD (round-robin); half = slot>>2 pins feature
// half 0 to XCDs 0-3 and half 1 to XCDs 4-7, so each XCD gathers from a 25.6 MB
// half-table instead of the full 51 MB (per-XCD distinct-byte floor halves).
// One dst per wave; wave-uniform edge loop (readfirstlane -> s_load for
// rowp/col/dinv). 4 feats/lane (8B row-chunk loads), 8-way unrolled.
__global__ __launch_bounds__(256) void prop1_kernel(const u16t* __restrict__ y1,
    const int* __restrict__ col, const int* __restrict__ rowp, const int* __restrict__ rowend,
    const float* __restrict__ dinv, const float* __restrict__ b1,
    float* __restrict__ embf, u16t* __restrict__ embb, int n, int nchunk) {
  const int b = blockIdx.x;
  const int slot = b & 7;
  const int hf = slot >> 2;
  const int chunk = (b >> 3) * 4 + (slot & 3);
  if (chunk >= nchunk) return;
  const int i = __builtin_amdgcn_readfirstlane(chunk * 4 + (threadIdx.x >> 6));
  if (i >= n) return;
  const int lane = threadIdx.x & 63;
  const int f = hf * 256 + lane * 4;

  const float di = dinv[i];
  const int e0 = rowp[i];
  const int e1 = rowend[i];

  float acc[4];
  short4v v = *(const short4v*)&y1[(size_t)i * 512 + f];
#pragma unroll
  for (int j = 0; j < 4; ++j) acc[j] = di * bf2f(v[j]);

  int e = e0;
  for (; e + 8 <= e1; e += 8) {
    int s[8];
    float w[8];
    short4v u[8];
#pragma unroll
    for (int q = 0; q < 8; ++q) s[q] = col[e + q];
#pragma unroll
    for (int q = 0; q < 8; ++q) w[q] = dinv[s[q]];
#pragma unroll
    for (int q = 0; q < 8; ++q) u[q] = *(const short4v*)&y1[(size_t)s[q] * 512 + f];
#pragma unroll
    for (int q = 0; q < 8; ++q)
#pragma unroll
      for (int j = 0; j < 4; ++j) acc[j] += w[q] * bf2f(u[q][j]);
  }
  for (; e < e1; ++e) {
    const int s = col[e];
    const float w = dinv[s];
    short4v u = *(const short4v*)&y1[(size_t)s * 512 + f];
#pragma unroll
    for (int j = 0; j < 4; ++j) acc[j] += w * bf2f(u[j]);
  }

  const unsigned flat = (unsigned)i * 512u + (unsigned)f;
  f32x4 o;
  short4v ob;
#pragma unroll
  for (int j = 0; j < 4; ++j) {
    float h = di * acc[j] + b1[f + j];
    h = fmaxf(h, 0.f);
    float eb = keep_mask(flat + (unsigned)j) ? 2.f * h : 0.f;
    o[j] = eb;
    ob[j] = (short)f2bf(eb);
  }
  *(f32x4*)&embf[(size_t)i * 512 + f] = o;
  *(short4v*)&embb[(size_t)i * 512 + f] = ob;
}

// ---- propagate layer 2, feature-split-2 with XCD affinity (same mapping) ----
// One dst per wave, 2 feats/lane (4B row-chunk loads), 8-way unrolled.
__global__ __launch_bounds__(256) void prop2_kernel(const u16t* __restrict__ z,
    const int* __restrict__ col, const int* __restrict__ rowp, const int* __restrict__ rowend,
    const float* __restrict__ dinv, const float* __restrict__ b2,
    float* __restrict__ outp, int n, int nchunk) {
  const int b = blockIdx.x;
  const int slot = b & 7;
  const int hf = slot >> 2;
  const int chunk = (b >> 3) * 4 + (slot & 3);
  if (chunk >= nchunk) return;
  const int i = __builtin_amdgcn_readfirstlane(chunk * 4 + (threadIdx.x >> 6));
  if (i >= n) return;
  const int lane = threadIdx.x & 63;
  const int f = hf * 128 + lane * 2;

  const float di = dinv[i];
  const int e0 = rowp[i];
  const int e1 = rowend[i];

  float acc[2];
  short2v v = *(const short2v*)&z[(size_t)i * 256 + f];
#pragma unroll
  for (int j = 0; j < 2; ++j) acc[j] = di * bf2f(v[j]);

  int e = e0;
  for (; e + 8 <= e1; e += 8) {
    int s[8];
    float w[8];
    short2v u[8];
#pragma unroll
    for (int q = 0; q < 8; ++q) s[q] = col[e + q];
#pragma unroll
    for (int q = 0; q < 8; ++q) w[q] = dinv[s[q]];
#pragma unroll
    for (int q = 0; q < 8; ++q) u[q] = *(const short2v*)&z[(size_t)s[q] * 256 + f];
#pragma unroll
    for (int q = 0; q < 8; ++q)
#pragma unroll
      for (int j = 0; j < 2; ++j) acc[j] += w[q] * bf2f(u[q][j]);
  }
  for (; e < e1; ++e) {
    const int s = col[e];
    const float w = dinv[s];
    short2v u = *(const short2v*)&z[(size_t)s * 256 + f];
#pragma unroll
    for (int j = 0; j < 2; ++j) acc[j] += w * bf2f(u[j]);
  }

  f32x2 o;
#pragma unroll
  for (int j = 0; j < 2; ++j) o[j] = di * acc[j] + b2[f + j];
  *(f32x2*)&outp[(size_t)i * 256 + f] = o;
}

extern "C" void kernel_launch(void* const* d_in, const int* in_sizes, int n_in,
                              void* d_out, int out_size, void* d_ws, size_t ws_size,
                              hipStream_t stream) {
  (void)n_in; (void)out_size; (void)ws_size;
  const float* x  = (const float*)d_in[0];
  const int*   ei = (const int*)d_in[1];    // [2][E]: src row then dst row
  const float* W1 = (const float*)d_in[2];
  const float* b1 = (const float*)d_in[3];
  const float* W2 = (const float*)d_in[4];
  const float* b2 = (const float*)d_in[5];

  const int Nn = in_sizes[0] / 512;             // 50000
  const int E  = in_sizes[1] / 2;               // 800000
  const int Mpad = ((Nn + 127) / 128) * 128;    // 50048
  const int K = 512;

  char* ws = (char*)d_ws;
  size_t off = 0;
  auto take = [&](size_t bytes) -> char* {
    char* p = ws + off;
    off += (bytes + 255) & ~(size_t)255;
    return p;
  };
  u16t* xb   = (u16t*)take((size_t)Mpad * 512 * 2);  // x bf16; later reused as emb bf16
  u16t* y1b  = (u16t*)take((size_t)Mpad * 512 * 2);  // y1 = x@W1^T bf16; later reused as z
  u16t* W1b  = (u16t*)take((size_t)512 * 512 * 2);
  u16t* W2b  = (u16t*)take((size_t)256 * 512 * 2);
  int*   cnt    = (int*)take((size_t)(Nn + 1) * 4);  // cnt[Nn] is the global cursor
  int*   rowp   = (int*)take((size_t)Nn * 4);
  int*   cursor = (int*)take((size_t)Nn * 4);
  float* dinv   = (float*)take((size_t)Nn * 4);
  int*   colA   = (int*)take((size_t)E * 4);

  float* embf = (float*)d_out;                       // [Nn,512]
  float* outf = (float*)d_out + (size_t)Nn * 512;    // [Nn,256]

  hipMemsetAsync(cnt, 0, (size_t)(Nn + 1) * 4, stream);

  const int n1 = Nn * 512;
  cvt_bf16<<<(n1 / 4 + 255) / 256, 256, 0, stream>>>(x, xb, n1);
  cvt_bf16<<<(512 * 512 / 4 + 255) / 256, 256, 0, stream>>>(W1, W1b, 512 * 512);
  cvt_bf16<<<(256 * 512 / 4 + 255) / 256, 256, 0, stream>>>(W2, W2b, 256 * 512);

  count_edges<<<(E + 255) / 256, 256, 0, stream>>>(ei + E, E, cnt);
  rowp_build<<<(Nn + 255) / 256, 256, 0, stream>>>(cnt, rowp, cursor, dinv, cnt + Nn, Nn);
  fill_csr<<<(E + 255) / 256, 256, 0, stream>>>(ei, ei + E, E, cursor, colA);

  // split-grid size: nchunk 4-node chunks per half, grouped 4 chunks x 8 slots
  const int nchunk = (Nn + 3) / 4;             // 12500
  const int nblk_split = ((nchunk + 3) / 4) * 8;  // 25000

  // layer 1: y1 = x @ W1^T (bf16), then propagate (P commutes with right-mul)
  dim3 g1(512 / 128, Mpad / 128);
  gemm_bt<<<g1, 256, 0, stream>>>(xb, W1b, y1b, K, 512);
  prop1_kernel<<<nblk_split, 256, 0, stream>>>(y1b, colA, rowp, cursor, dinv, b1,
                                               embf, xb /* emb bf16 */, Nn, nchunk);

  // layer 2: z = emb @ W2^T (bf16), then propagate + b2
  u16t* zb = y1b;  // alias: y1 dead after prop1
  dim3 g2(256 / 128, Mpad / 128);
  gemm_bt<<<g2, 256, 0, stream>>>(xb, W2b, zb, K, 256);
  prop2_kernel<<<nblk_split, 256, 0, stream>>>(zb, colA, rowp, cursor, dinv, b2, outf, Nn, nchunk);
}